// Round 4
// baseline (1039.259 us; speedup 1.0000x reference)
//
#include <hip/hip_runtime.h>

// SpinalCPG: T sequential steps, B=2048 independent batch elements, 32 neurons each.
// Layout: 1 lane = 1 neuron; wave64 = 2 batch elements.
// Numerics: must match NumPy f32 exactly (spike threshold is bit-sensitive):
//   - fp contract OFF (no FMA)
//   - 8-mean: pairwise tree ((a0+a1)+(a2+a3))+((a4+a5)+(a6+a7)), valid at all lanes (commutativity)
//   - 4-mean: sequential ((a0+a1)+a2)+a3, valid at quad-base lanes only; consumers
//     shuffle from base lanes (0,8,16,24 / +32 for upper batch half).

__global__ __launch_bounds__(256) void cpg_kernel(
    const float* __restrict__ drive,   // [T,B]
    const float* __restrict__ turnb,   // [T,B]
    const float* __restrict__ noise,   // [T,B,32]
    const float* __restrict__ v0,      // [B,32]
    const float* __restrict__ syn0,    // [B,32]
    float* __restrict__ out,           // [T,B,4]
    int T, int B)
{
#pragma clang fp contract(off)
    const int gtid = blockIdx.x * blockDim.x + threadIdx.x; // [0, B*32)
    const int b = gtid >> 5;           // global batch index
    const int n = gtid & 31;           // neuron index within batch element
    const int lane = threadIdx.x & 63;
    const int half = lane & 32;        // which 32-lane half of the wave

    // rate source lane (base lane of the source population), within wave
    const int srcN = (n < 8) ? 24 : (n < 16) ? 0 : (n < 24) ? 8 : 16;
    const int srcLane = half | srcN;
    // synaptic weight onto this neuron
    const float wmul = (n < 8)  ? -1.0f
                     : (n < 12) ?  0.6f
                     : (n < 16) ?  0.8f
                     : (n < 24) ? -1.0f
                     : (n < 28) ?  0.6f
                     :             0.8f;
    const bool isExc = (n < 8) || (n >= 16 && n < 24);
    const bool isR   = (n >= 16);
    const float rateScale = isExc ? 0.125f : 0.25f;   // /8 or /4 (exact)
    const int idx2 = (lane & ~3) | 2;
    const int idx3 = (lane & ~3) | 3;
    const int mlLane = half | 12;
    const int mrLane = half | 28;

    float v   = v0[gtid];
    float syn = syn0[gtid];

    const float C1 = 1.0f - 0.7f;      // f32-exact 0.30000001192...

    constexpr int PF = 8;              // prefetch depth (T=1000 divisible by 8)
    float eps_pf[PF], d_pf[PF], tb_pf[PF];
#pragma unroll
    for (int i = 0; i < PF; ++i) {
        eps_pf[i] = noise[(size_t)i * (B * 32) + gtid];
        d_pf[i]   = drive[i * B + b];
        tb_pf[i]  = turnb[i * B + b];
    }

    for (int t0 = 0; t0 < T; t0 += PF) {
#pragma unroll
        for (int i = 0; i < PF; ++i) {
            const int t = t0 + i;
            const float eps = eps_pf[i];
            const float d   = d_pf[i];
            const float tb  = tb_pf[i];
            const int tn = t + PF;
            if (tn < T) {
                eps_pf[i] = noise[(size_t)tn * (B * 32) + gtid];
                d_pf[i]   = drive[tn * B + b];
                tb_pf[i]  = turnb[tn * B + b];
            }

            // ---- population rates from syn (previous step's syn) ----
            float t1 = syn + __shfl_xor(syn, 1);
            float t2 = t1 + __shfl_xor(t1, 2);
            float s8 = t2 + __shfl_xor(t2, 4);      // np 8-sum (identical across 8-group)
            float u2 = t1 + __shfl(syn, idx2);
            float u3 = u2 + __shfl(syn, idx3);      // np sequential 4-sum (valid at quad base)
            float pub  = (isExc ? s8 : u3) * rateScale;
            float rate = __shfl(pub, srcLane);

            // ---- membrane update ----
            float Isyn = wmul * rate;
            float tbs  = isR ? -tb : tb;
            float dr   = d + fmaxf(0.0f, tbs) * 0.3f;
            float Iext = isExc ? dr : 0.0f;
            float accv = (Iext + Isyn) + eps * 0.08f;
            float vn   = 0.7f * v + C1 * accv;
            bool spiked = (vn >= 0.5f);
            v = spiked ? 0.0f : vn;
            float spk = spiked ? 1.0f : 0.0f;
            syn = 0.8f * syn + spk;

            // ---- motor outputs from new syn ----
            float m1 = syn + __shfl_xor(syn, 1);
            float m2 = m1 + __shfl(syn, idx2);
            float m3 = m2 + __shfl(syn, idx3);      // np 4-sum at quad base (lanes 12, 28)
            float motor = m3 * 0.25f;
            float mL = __shfl(motor, mlLane);
            float mR = __shfl(motor, mrLane);
            if (n < 4) {
                float val = (n == 0) ? mL
                          : (n == 1) ? mR
                          : (n == 2) ? (mL + mR) * 0.5f
                          :            (mR - mL) * 2.0f;
                out[(size_t)t * (B * 4) + b * 4 + n] = val;
            }
        }
    }
}

extern "C" void kernel_launch(void* const* d_in, const int* in_sizes, int n_in,
                              void* d_out, int out_size, void* d_ws, size_t ws_size,
                              hipStream_t stream) {
    const float* drive = (const float*)d_in[0];
    const float* turnb = (const float*)d_in[1];
    const float* noise = (const float*)d_in[2];
    const float* v0    = (const float*)d_in[3];
    const float* syn0  = (const float*)d_in[4];
    float* out = (float*)d_out;
    const int B = 2048;
    const int T = in_sizes[0] / B;
    const int threads = 256;
    const int total = B * 32;           // one lane per neuron
    cpg_kernel<<<total / threads, threads, 0, stream>>>(drive, turnb, noise, v0, syn0, out, T, B);
}

// Round 7
// 1014.851 us; speedup vs baseline: 1.0241x; 1.0241x over previous
//
#include <hip/hip_runtime.h>

// SpinalCPG: T serial steps, B=2048 batches, 32 neurons. Latency-bound serial chain.
// Round-7: one batch per wave64 (both halves duplicate work; 2048 waves = 2/SIMD for
// latency interleave). Cross-lane ops restricted to:
//   - DPP quad_perm 0xB1 (xor1), 0x4E (xor2), 0x00 (quad-base bcast)  [VALU pipe]
//   - ds_swizzle bit-mode XOR (documented family): 0x101F(^4) 0x201F(^8) 0x301F(^12)
//     0x601F(^24) 0x701F(^28)                                          [LDS pipe]
// NO row_mirror/row_half_mirror/row_shl/row_shr/lane-bcast quad_perms (rounds 5-6
// failed with those; they are the unique suspects common to both failures).
// Numerics bit-identical to PASSING round-4 kernel (absmax 0.03125 = canary):
//   8-sum: tree ((a0+a1)+(a2+a3))+((a4+a5)+(a6+a7)) [np pairwise n=8]
//   4-sum: sequential ((a0+a1)+a2)+a3 at quad base, then broadcast [np n<8]
//   fp contract OFF; means via *0.25f / *0.125f (exact).

template<int CTRL>
__device__ __forceinline__ float dppf(float x) {
    return __int_as_float(__builtin_amdgcn_update_dpp(
        0, __float_as_int(x), CTRL, 0xF, 0xF, true));
}
template<int IMM>
__device__ __forceinline__ float swzf(float x) {
    return __int_as_float(__builtin_amdgcn_ds_swizzle(__float_as_int(x), IMM));
}

__global__ __launch_bounds__(256) void cpg_kernel(
    const float* __restrict__ drive,   // [T,B]
    const float* __restrict__ turnb,   // [T,B]
    const float* __restrict__ noise,   // [T,B,32]
    const float* __restrict__ v0,      // [B,32]
    const float* __restrict__ syn0,    // [B,32]
    float* __restrict__ out,           // [T,B,4]
    int T, int B)
{
#pragma clang fp contract(off)
    const int tid  = blockIdx.x * blockDim.x + threadIdx.x;
    const int b    = tid >> 6;         // one batch per wave64
    const int lane = threadIdx.x & 63;
    const int n    = lane & 31;        // neuron index (both halves duplicate)
    const int r    = n & 15;           // 0..7 exc, 8..11 inh, 12..15 mot

    const bool isExc = (r < 8);
    const bool isR   = (n >= 16);
    const bool hi4   = (n & 4) != 0;
    const float wmul  = isExc ? -1.0f : ((r < 12) ? 0.6f : 0.8f);
    const float scale = isExc ? 0.25f : 0.125f;

    const int sidx = b * 32 + n;
    float v   = v0[sidx];
    float syn = syn0[sidx];
    const float C1 = 1.0f - 0.7f;      // f32-exact

    float rate, mOwn, mOpp;
    auto reduce = [&](float s) {
        float w1  = dppf<0xB1>(s);                 // s[l^1]
        float t1  = s + w1;                        // pair sums (a0+a1 at base)
        float w2  = dppf<0x4E>(s);                 // s[l^2]  (a2 at base)
        float w3  = dppf<0x4E>(w1);                // s[l^3]  (a3 at base)
        float u2  = t1 + w2;                       // (a0+a1)+a2 at base
        float Q4v = u2 + w3;                       // ((a0+a1)+a2)+a3 at base  [np seq 4-sum]
        float Q4  = dppf<0x00>(Q4v);               // quad-uniform
        float t2  = t1 + dppf<0x4E>(t1);           // tree quad sum (quad-uniform bitwise)
        float S8  = t2 + swzf<0x101F>(t2);         // ^4: tree 8-sum (8-group uniform)
        float QXa = swzf<0x601F>(Q4);              // ^24: opp-inh for exc r=0..3
        float QXb = swzf<0x701F>(Q4);              // ^28: opp-inh for exc r=4..7; opp-mot for n<4
        float EX  = swzf<0x201F>(S8);              // ^8 : own-exc 8-sum for inh/mot
        mOwn = swzf<0x301F>(Q4);                   // ^12: own-mot quad sum for n<4
        mOpp = QXb;
        float QX  = hi4 ? QXb : QXa;
        rate = (isExc ? QX : EX) * scale;
    };

    reduce(syn);                        // rates for step 0 (syn0)

    constexpr int PF = 20;              // prefetch depth (T=1000 divisible by 20)
    float eps_pf[PF], d_pf[PF], tb_pf[PF];
#pragma unroll
    for (int i = 0; i < PF; ++i) {
        eps_pf[i] = noise[(size_t)i * (B * 32) + sidx];
        d_pf[i]   = drive[i * B + b];
        tb_pf[i]  = turnb[i * B + b];
    }

    for (int t0 = 0; t0 < T; t0 += PF) {
#pragma unroll
        for (int i = 0; i < PF; ++i) {
            const int t = t0 + i;
            const float eps = eps_pf[i];
            const float d   = d_pf[i];
            const float tb  = tb_pf[i];
            const int tn = t + PF;
            if (tn < T) {
                eps_pf[i] = noise[(size_t)tn * (B * 32) + sidx];
                d_pf[i]   = drive[tn * B + b];
                tb_pf[i]  = turnb[tn * B + b];
            }

            // ---- membrane update (rate from previous reduce) ----
            float Isyn = wmul * rate;
            float tbs  = isR ? -tb : tb;
            float dr   = d + fmaxf(0.0f, tbs) * 0.3f;
            float Iext = isExc ? dr : 0.0f;
            float accv = (Iext + Isyn) + eps * 0.08f;
            float vn   = 0.7f * v + C1 * accv;
            bool spiked = (vn >= 0.5f);
            v = spiked ? 0.0f : vn;
            syn = 0.8f * syn + (spiked ? 1.0f : 0.0f);

            // ---- reduce new syn: rate for t+1, motor sums for t ----
            reduce(syn);

            // ---- outputs (lanes 0..3 only; mOwn/mOpp valid there) ----
            if (lane < 4) {
                float mL = mOwn * 0.25f;
                float mR = mOpp * 0.25f;
                float val = (lane == 0) ? mL
                          : (lane == 1) ? mR
                          : (lane == 2) ? (mL + mR) * 0.5f
                          :               (mR - mL) * 2.0f;
                out[(size_t)t * (B * 4) + b * 4 + lane] = val;
            }
        }
    }
}

extern "C" void kernel_launch(void* const* d_in, const int* in_sizes, int n_in,
                              void* d_out, int out_size, void* d_ws, size_t ws_size,
                              hipStream_t stream) {
    const float* drive = (const float*)d_in[0];
    const float* turnb = (const float*)d_in[1];
    const float* noise = (const float*)d_in[2];
    const float* v0    = (const float*)d_in[3];
    const float* syn0  = (const float*)d_in[4];
    float* out = (float*)d_out;
    const int B = in_sizes[3] / 32;
    const int T = in_sizes[0] / B;
    const int threads = 256;
    const int total = B * 64;           // one batch per wave64 (duplicated halves)
    cpg_kernel<<<total / threads, threads, 0, stream>>>(drive, turnb, noise, v0, syn0, out, T, B);
}

// Round 8
// 538.105 us; speedup vs baseline: 1.9313x; 1.8860x over previous
//
#include <hip/hip_runtime.h>

// SpinalCPG: T serial steps, B=2048 batches, 32 neurons. One batch per wave64
// (duplicated halves), 2048 waves = 2/SIMD. Round-7 reduce() kept VERBATIM
// (passed with exact canary 0.03125).
// Round-8 change: chunked burst-load/compute/burst-store. Theory: flat loads
// count in BOTH vmcnt and lgkmcnt; with a rolling prefetch in flight, every
// lgkmcnt wait before a swizzle result drained the whole HBM pipeline each
// step (~1850 cyc/step, identical across rounds 4 & 7). Now the compute phase
// has ZERO outstanding vmem: burst 60 loads -> vmcnt(0) -> 20 pure-register
// steps -> burst store.

template<int CTRL>
__device__ __forceinline__ float dppf(float x) {
    return __int_as_float(__builtin_amdgcn_update_dpp(
        0, __float_as_int(x), CTRL, 0xF, 0xF, true));
}
template<int IMM>
__device__ __forceinline__ float swzf(float x) {
    return __int_as_float(__builtin_amdgcn_ds_swizzle(__float_as_int(x), IMM));
}

__global__ __launch_bounds__(256) void cpg_kernel(
    const float* __restrict__ drive,   // [T,B]
    const float* __restrict__ turnb,   // [T,B]
    const float* __restrict__ noise,   // [T,B,32]
    const float* __restrict__ v0,      // [B,32]
    const float* __restrict__ syn0,    // [B,32]
    float* __restrict__ out,           // [T,B,4]
    int T, int B)
{
#pragma clang fp contract(off)
    const int tid  = blockIdx.x * blockDim.x + threadIdx.x;
    const int b    = tid >> 6;         // one batch per wave64
    const int lane = threadIdx.x & 63;
    const int n    = lane & 31;        // neuron index (halves duplicate)
    const int r    = n & 15;           // 0..7 exc, 8..11 inh, 12..15 mot

    const bool isExc = (r < 8);
    const bool isR   = (n >= 16);
    const bool hi4   = (n & 4) != 0;
    const float wmul  = isExc ? -1.0f : ((r < 12) ? 0.6f : 0.8f);
    const float scale = isExc ? 0.25f : 0.125f;

    const int sidx = b * 32 + n;
    float v   = v0[sidx];
    float syn = syn0[sidx];
    const float C1 = 1.0f - 0.7f;      // f32-exact

    float rate, mOwn, mOpp;
    // VERBATIM round-7 reduce (canary-exact numerics).
    auto reduce = [&](float s) {
        float w1  = dppf<0xB1>(s);                 // s[l^1]
        float t1  = s + w1;                        // pair sums
        float w2  = dppf<0x4E>(s);                 // s[l^2]
        float w3  = dppf<0x4E>(w1);                // s[l^3]
        float u2  = t1 + w2;                       // (a0+a1)+a2 at base
        float Q4v = u2 + w3;                       // ((a0+a1)+a2)+a3 at base
        float Q4  = dppf<0x00>(Q4v);               // quad-uniform
        float t2  = t1 + dppf<0x4E>(t1);           // tree quad sum
        float S8  = t2 + swzf<0x101F>(t2);         // ^4: tree 8-sum
        float QXa = swzf<0x601F>(Q4);              // ^24: opp-inh for exc r=0..3
        float QXb = swzf<0x701F>(Q4);              // ^28: opp-inh r=4..7; opp-mot n<4
        float EX  = swzf<0x201F>(S8);              // ^8 : own-exc 8-sum
        mOwn = swzf<0x301F>(Q4);                   // ^12: own-mot quad for n<4
        mOpp = QXb;
        float QX  = hi4 ? QXb : QXa;
        rate = (isExc ? QX : EX) * scale;
    };

    reduce(syn);                        // rates for step 0

    constexpr int C = 20;               // chunk size (T=1000 divisible by 20)
    float eps_r[C], d_r[C], tb_r[C], out_r[C];

    const float* np_ = noise + sidx;
    const float* dp_ = drive + b;
    const float* tp_ = turnb + b;

    for (int t0 = 0; t0 < T; t0 += C) {
        // ---- burst load: 3*C independent loads, then full drain ----
#pragma unroll
        for (int i = 0; i < C; ++i) {
            const size_t t = (size_t)(t0 + i);
            eps_r[i] = np_[t * (size_t)(B * 32)];
            d_r[i]   = dp_[t * (size_t)B];
            tb_r[i]  = tp_[t * (size_t)B];
        }
        asm volatile("s_waitcnt vmcnt(0)" ::: "memory");
        __builtin_amdgcn_sched_barrier(0);

        // ---- C steps of pure register/LDS-pipe compute ----
#pragma unroll
        for (int i = 0; i < C; ++i) {
            const float eps = eps_r[i];
            const float d   = d_r[i];
            const float tb  = tb_r[i];

            float Isyn = wmul * rate;
            float tbs  = isR ? -tb : tb;
            float dr   = d + fmaxf(0.0f, tbs) * 0.3f;
            float Iext = isExc ? dr : 0.0f;
            float accv = (Iext + Isyn) + eps * 0.08f;
            float vn   = 0.7f * v + C1 * accv;
            bool spiked = (vn >= 0.5f);
            v = spiked ? 0.0f : vn;
            syn = 0.8f * syn + (spiked ? 1.0f : 0.0f);

            reduce(syn);                // rate for t+1, motor sums for t

            float mL = mOwn * 0.25f;
            float mR = mOpp * 0.25f;
            out_r[i] = (lane == 0) ? mL
                     : (lane == 1) ? mR
                     : (lane == 2) ? (mL + mR) * 0.5f
                     :               (mR - mL) * 2.0f;
        }

        // ---- burst store (lanes 0..3 only) ----
        if (lane < 4) {
#pragma unroll
            for (int i = 0; i < C; ++i) {
                out[(size_t)(t0 + i) * (B * 4) + b * 4 + lane] = out_r[i];
            }
        }
    }
}

extern "C" void kernel_launch(void* const* d_in, const int* in_sizes, int n_in,
                              void* d_out, int out_size, void* d_ws, size_t ws_size,
                              hipStream_t stream) {
    const float* drive = (const float*)d_in[0];
    const float* turnb = (const float*)d_in[1];
    const float* noise = (const float*)d_in[2];
    const float* v0    = (const float*)d_in[3];
    const float* syn0  = (const float*)d_in[4];
    float* out = (float*)d_out;
    const int B = in_sizes[3] / 32;
    const int T = in_sizes[0] / B;
    const int threads = 256;
    const int total = B * 64;           // one batch per wave64 (duplicated halves)
    cpg_kernel<<<total / threads, threads, 0, stream>>>(drive, turnb, noise, v0, syn0, out, T, B);
}